// Round 2
// baseline (647.665 us; speedup 1.0000x reference)
//
#include <hip/hip_runtime.h>
#include <hip/hip_bf16.h>

typedef __attribute__((ext_vector_type(8))) short short8_t;
typedef __attribute__((ext_vector_type(4))) float f32x4_t;
typedef __attribute__((ext_vector_type(2))) float f32x2_t;

#define NHEAD 4
#define SCALE 0.17677669529663687f

// workspace layout (bytes)
#define OFF_W    0L          // weights bf16: qkv(49152) proj(16384) fc1(65536) fc2(65536) = 196608 elems
#define OFF_TBL  393216L     // rpe table t[225][4] f32
#define OFF_QKV  458752L     // qkv bf16 [131072][384]   (later reused as x1 f32 [131072][128])
#define OFF_X1   458752L
#define OFF_H    67567616L   // h bf16 [131072][512] (overwrites attn+proj regions, both dead)
#define OFF_ATTN 101122048L  // attn_out bf16 [131072][128]
#define OFF_PROJ 134676480L  // proj_out f32 [131072][128]
// total ws use: 201,785,344 bytes

__device__ __forceinline__ unsigned short f2bf(float f){
  unsigned int u = __float_as_uint(f);
  u += 0x7FFFu + ((u >> 16) & 1u);          // RNE
  return (unsigned short)(u >> 16);
}
__device__ __forceinline__ float bf2f(unsigned short s){
  return __uint_as_float(((unsigned int)s) << 16);
}

// windowed (shifted) row r  <->  original token index. Works both directions:
// QKV A-gather (read x at orig) and proj scatter (write out at orig).
__device__ __forceinline__ int win_row_to_orig(int r){
  int win = r >> 6, n = r & 63;
  int b = win >> 6, wh = (win >> 3) & 7, ww = win & 7;
  int hs = wh*8 + (n >> 3), wsv = ww*8 + (n & 7);
  return (b << 12) + (((hs + 4) & 63) << 6) + ((wsv + 4) & 63);
}

// ---------------- prep: weights -> bf16, RPE MLP table ----------------
__global__ __launch_bounds__(256) void prep_kernel(
    const float* __restrict__ qkv_w, const float* __restrict__ proj_w,
    const float* __restrict__ fc1_w, const float* __restrict__ fc2_w,
    const float* __restrict__ rpe_w1, const float* __restrict__ rpe_b1,
    const float* __restrict__ rpe_w2,
    unsigned short* __restrict__ wbf, float* __restrict__ tbl)
{
  if (blockIdx.x == 0) {
    int t = threadIdx.x;
    if (t < 225) {
      int a = t / 15, b = t % 15;
      float v0 = (float)(a - 7) * (8.0f / 7.0f);
      float v1 = (float)(b - 7) * (8.0f / 7.0f);
      float c0 = (v0 > 0.f ? 1.f : (v0 < 0.f ? -1.f : 0.f)) * log2f(fabsf(v0) + 1.f) * (1.0f/3.0f);
      float c1 = (v1 > 0.f ? 1.f : (v1 < 0.f ? -1.f : 0.f)) * log2f(fabsf(v1) + 1.f) * (1.0f/3.0f);
      float a0 = 0.f, a1 = 0.f, a2 = 0.f, a3 = 0.f;
      for (int k = 0; k < 512; k++){
        float h = c0 * rpe_w1[2*k] + c1 * rpe_w1[2*k+1] + rpe_b1[k];
        h = fmaxf(h, 0.f);
        a0 += h * rpe_w2[k];
        a1 += h * rpe_w2[512 + k];
        a2 += h * rpe_w2[1024 + k];
        a3 += h * rpe_w2[1536 + k];
      }
      tbl[t*4+0] = a0; tbl[t*4+1] = a1; tbl[t*4+2] = a2; tbl[t*4+3] = a3;
    }
  } else {
    int e = (blockIdx.x - 1) * 256 + threadIdx.x;   // 0..196607
    float v;
    if (e < 49152)       v = qkv_w[e];
    else if (e < 65536)  v = proj_w[e - 49152];
    else if (e < 131072) v = fc1_w[e - 65536];
    else                 v = fc2_w[e - 131072];
    wbf[e] = f2bf(v);
  }
}

// ---------------- GEMM: out[M][N] = A[M][K] * W[N][K]^T + bias ----------------
// AMODE: 0 = A f32 direct rows, 1 = A f32 with window-gather rows, 2 = A bf16 direct
// EPI:   0 = +bias -> bf16 store, 1 = +bias -> f32 store with window-scatter rows,
//        2 = +bias, exact GELU -> bf16, 3 = +bias -> f32
template<int N, int K, int AMODE, int EPI>
__global__ __launch_bounds__(256) void gemm_kernel(
    const void* __restrict__ Ap, const unsigned short* __restrict__ Bw,
    const float* __restrict__ bias, void* __restrict__ Out)
{
  constexpr int NT = N / 16;
  constexpr int KC = K / 32;
  __shared__ __align__(16) unsigned short bs[N * 40];  // [N][32] bf16, padded to 40 (2-way = free)
  int lane = threadIdx.x & 63;
  int wave = threadIdx.x >> 6;
  int m0 = blockIdx.x * 64 + wave * 16;
  int l15 = lane & 15;
  int kg  = lane >> 4;
  int arow = m0 + l15;
  int ag = (AMODE == 1) ? win_row_to_orig(arow) : arow;

  f32x4_t acc[NT];
#pragma unroll
  for (int t = 0; t < NT; t++) acc[t] = (f32x4_t){0.f, 0.f, 0.f, 0.f};

  for (int kc = 0; kc < KC; ++kc){
    if (kc) __syncthreads();
    // stage W chunk [N][32] bf16 into LDS
    for (int e = threadIdx.x; e < N * 4; e += 256){
      int n = e >> 2, k8 = e & 3;
      short8_t v = *(const short8_t*)(Bw + n * K + kc * 32 + k8 * 8);
      *(short8_t*)(&bs[n * 40 + k8 * 8]) = v;
    }
    __syncthreads();

    short8_t af;
    if (AMODE == 2) {
      af = *(const short8_t*)((const unsigned short*)Ap + (long)ag * K + kc * 32 + kg * 8);
    } else {
      const float* ap = (const float*)Ap + (long)ag * K + kc * 32 + kg * 8;
      f32x4_t a0 = *(const f32x4_t*)ap;
      f32x4_t a1 = *(const f32x4_t*)(ap + 4);
      union { short8_t v; unsigned short u[8]; } pk;
      pk.u[0] = f2bf(a0[0]); pk.u[1] = f2bf(a0[1]); pk.u[2] = f2bf(a0[2]); pk.u[3] = f2bf(a0[3]);
      pk.u[4] = f2bf(a1[0]); pk.u[5] = f2bf(a1[1]); pk.u[6] = f2bf(a1[2]); pk.u[7] = f2bf(a1[3]);
      af = pk.v;
    }
#pragma unroll
    for (int t = 0; t < NT; t++){
      short8_t bf = *(const short8_t*)(&bs[(t * 16 + l15) * 40 + kg * 8]);
      acc[t] = __builtin_amdgcn_mfma_f32_16x16x32_bf16(af, bf, acc[t], 0, 0, 0);
    }
  }

  int orow[4];
#pragma unroll
  for (int i = 0; i < 4; i++){
    int r = m0 + kg * 4 + i;
    orow[i] = (EPI == 1) ? win_row_to_orig(r) : r;
  }
#pragma unroll
  for (int t = 0; t < NT; t++){
    int col = t * 16 + l15;
    float bv = bias[col];
#pragma unroll
    for (int i = 0; i < 4; i++){
      float v = acc[t][i] + bv;
      if (EPI == 0) {
        ((unsigned short*)Out)[(long)orow[i] * N + col] = f2bf(v);
      } else if (EPI == 1) {
        ((float*)Out)[(long)orow[i] * N + col] = v;
      } else if (EPI == 2) {
        float g = 0.5f * v * (1.f + erff(v * 0.70710678118f));
        ((unsigned short*)Out)[(long)orow[i] * N + col] = f2bf(g);
      } else {
        ((float*)Out)[(long)orow[i] * N + col] = v;
      }
    }
  }
}

// ---------------- per-window attention ----------------
// block = 1 window, 4 waves = 4 heads, lane = query token
__global__ __launch_bounds__(256) void attn_kernel(
    const unsigned short* __restrict__ qkv, const float* __restrict__ tbl,
    unsigned short* __restrict__ outp)
{
  __shared__ float kv[2][NHEAD][64][32];   // 64 KB, K and V as f32
  __shared__ float tl[900];
  __shared__ unsigned char regid[64];
  int win = blockIdx.x;
  int head = threadIdx.x >> 6;
  int lane = threadIdx.x & 63;

  // stage K,V (bf16 -> f32)
  for (int e = threadIdx.x; e < 2048; e += 256){
    int c8 = e & 15, tok = (e >> 4) & 63, sel = e >> 10;
    short8_t v = *(const short8_t*)(qkv + (long)(win * 64 + tok) * 384 + 128 + sel * 128 + c8 * 8);
    int c = c8 * 8;
    float* dst = &kv[sel][c >> 5][tok][c & 31];
    union { short8_t v; unsigned short u[8]; } pk; pk.v = v;
#pragma unroll
    for (int i = 0; i < 8; i++) dst[i] = bf2f(pk.u[i]);
  }
  for (int e = threadIdx.x; e < 900; e += 256) tl[e] = tbl[e];
  if (threadIdx.x < 64){
    int wh = (win >> 3) & 7, ww = win & 7;
    int hs = wh * 8 + (threadIdx.x >> 3), wsv = ww * 8 + (threadIdx.x & 7);
    int rr = hs  < 56 ? 0 : (hs  < 60 ? 1 : 2);
    int cr = wsv < 56 ? 0 : (wsv < 60 ? 1 : 2);
    regid[threadIdx.x] = (unsigned char)(rr * 3 + cr);
  }
  __syncthreads();

  // Q row for (win, lane, head), pre-scaled
  float q[32];
  const unsigned short* qp = qkv + (long)(win * 64 + lane) * 384 + head * 32;
#pragma unroll
  for (int d = 0; d < 32; d += 8){
    union { short8_t v; unsigned short u[8]; } pk;
    pk.v = *(const short8_t*)(qp + d);
#pragma unroll
    for (int i = 0; i < 8; i++) q[d + i] = bf2f(pk.u[i]) * SCALE;
  }
  int i1 = lane >> 3, j1 = lane & 7;
  int myreg = regid[lane];

  float s[64];
  float mx = -1e30f;
#pragma unroll
  for (int m = 0; m < 64; m++){
    const f32x4_t* kr = (const f32x4_t*)kv[0][head][m];
    float a0 = 0.f, a1 = 0.f, a2 = 0.f, a3 = 0.f;
#pragma unroll
    for (int dd = 0; dd < 8; dd++){
      f32x4_t kk = kr[dd];
      a0 += q[dd*4+0] * kk[0]; a1 += q[dd*4+1] * kk[1];
      a2 += q[dd*4+2] * kk[2]; a3 += q[dd*4+3] * kk[3];
    }
    float acc = (a0 + a1) + (a2 + a3);
    int i2 = m >> 3, j2 = m & 7;
    acc += tl[((i1 - i2 + 7) * 15 + (j1 - j2 + 7)) * 4 + head];
    if (regid[m] != myreg) acc -= 100.f;
    s[m] = acc;
    mx = fmaxf(mx, acc);
  }
  float sum = 0.f;
#pragma unroll
  for (int m = 0; m < 64; m++){ float e = __expf(s[m] - mx); s[m] = e; sum += e; }
  float inv = 1.f / sum;

  float o[32];
#pragma unroll
  for (int d = 0; d < 32; d++) o[d] = 0.f;
#pragma unroll
  for (int m = 0; m < 64; m++){
    float p = s[m];
    const f32x4_t* vr = (const f32x4_t*)kv[1][head][m];
#pragma unroll
    for (int dd = 0; dd < 8; dd++){
      f32x4_t vv = vr[dd];
      o[dd*4+0] += p * vv[0]; o[dd*4+1] += p * vv[1];
      o[dd*4+2] += p * vv[2]; o[dd*4+3] += p * vv[3];
    }
  }
  unsigned short* op = outp + (long)(win * 64 + lane) * 128 + head * 32;
#pragma unroll
  for (int d0 = 0; d0 < 32; d0 += 8){
    union { short8_t v; unsigned short u[8]; } pk;
#pragma unroll
    for (int i = 0; i < 8; i++) pk.u[i] = f2bf(o[d0 + i] * inv);
    *(short8_t*)(op + d0) = pk.v;
  }
}

// ---------------- out = res + LayerNorm(in) * w + b ----------------
// NOTE: no __restrict__ on in/out — LN2 runs in-place on d_out.
__global__ __launch_bounds__(256) void ln_residual_kernel(
    const float* in, const float* __restrict__ res,
    const float* __restrict__ w, const float* __restrict__ b, float* out)
{
  int row = blockIdx.x * 4 + (threadIdx.x >> 6);
  int lane = threadIdx.x & 63;
  long base = (long)row * 128 + lane * 2;
  f32x2_t v = *(const f32x2_t*)(in + base);
  float sm = v[0] + v[1];
#pragma unroll
  for (int off = 1; off < 64; off <<= 1) sm += __shfl_xor(sm, off);
  float mu = sm * 0.0078125f;
  float d0 = v[0] - mu, d1 = v[1] - mu;
  float qv = d0 * d0 + d1 * d1;
#pragma unroll
  for (int off = 1; off < 64; off <<= 1) qv += __shfl_xor(qv, off);
  float rs = rsqrtf(qv * 0.0078125f + 1e-5f);
  f32x2_t r = *(const f32x2_t*)(res + base);
  f32x2_t o;
  o[0] = r[0] + d0 * rs * w[lane*2]     + b[lane*2];
  o[1] = r[1] + d1 * rs * w[lane*2 + 1] + b[lane*2 + 1];
  *(f32x2_t*)(out + base) = o;
}

extern "C" void kernel_launch(void* const* d_in, const int* in_sizes, int n_in,
                              void* d_out, int out_size, void* d_ws, size_t ws_size,
                              hipStream_t stream)
{
  (void)in_sizes; (void)n_in; (void)out_size; (void)ws_size;
  const float* x      = (const float*)d_in[0];
  const float* qkv_w  = (const float*)d_in[1];
  const float* qkv_b  = (const float*)d_in[2];
  const float* proj_w = (const float*)d_in[3];
  const float* proj_b = (const float*)d_in[4];
  const float* rpe_w1 = (const float*)d_in[5];
  const float* rpe_b1 = (const float*)d_in[6];
  const float* rpe_w2 = (const float*)d_in[7];
  const float* n1w    = (const float*)d_in[8];
  const float* n1b    = (const float*)d_in[9];
  const float* fc1_w  = (const float*)d_in[10];
  const float* fc1_b  = (const float*)d_in[11];
  const float* fc2_w  = (const float*)d_in[12];
  const float* fc2_b  = (const float*)d_in[13];
  const float* n2w    = (const float*)d_in[14];
  const float* n2b    = (const float*)d_in[15];

  char* ws = (char*)d_ws;
  unsigned short* Wbf   = (unsigned short*)(ws + OFF_W);
  float*          tblp  = (float*)(ws + OFF_TBL);
  unsigned short* qkvp  = (unsigned short*)(ws + OFF_QKV);
  unsigned short* attnp = (unsigned short*)(ws + OFF_ATTN);
  float*          projp = (float*)(ws + OFF_PROJ);
  float*          x1p   = (float*)(ws + OFF_X1);
  unsigned short* hp    = (unsigned short*)(ws + OFF_H);
  float*          yp    = (float*)d_out;

  prep_kernel<<<769, 256, 0, stream>>>(qkv_w, proj_w, fc1_w, fc2_w, rpe_w1, rpe_b1, rpe_w2, Wbf, tblp);
  // QKV: windowed rows, gather x through roll+partition
  gemm_kernel<384, 128, 1, 0><<<2048, 256, 0, stream>>>(x, Wbf, qkv_b, qkvp);
  attn_kernel<<<2048, 256, 0, stream>>>(qkvp, tblp, attnp);
  // proj: scatter rows back to original token order
  gemm_kernel<128, 128, 2, 1><<<2048, 256, 0, stream>>>(attnp, Wbf + 49152, proj_b, projp);
  ln_residual_kernel<<<32768, 256, 0, stream>>>(projp, x, n1w, n1b, x1p);
  gemm_kernel<512, 128, 0, 2><<<2048, 256, 0, stream>>>(x1p, Wbf + 65536, fc1_b, hp);
  gemm_kernel<128, 512, 2, 3><<<2048, 256, 0, stream>>>(hp, Wbf + 131072, fc2_b, yp);
  ln_residual_kernel<<<32768, 256, 0, stream>>>(yp, x1p, n2w, n2b, (float*)d_out);
}

// Round 3
// 508.827 us; speedup vs baseline: 1.2729x; 1.2729x over previous
//
#include <hip/hip_runtime.h>
#include <hip/hip_bf16.h>

typedef __attribute__((ext_vector_type(8))) short short8_t;
typedef __attribute__((ext_vector_type(4))) float f32x4_t;
typedef __attribute__((ext_vector_type(2))) float f32x2_t;

#define NHEAD 4
#define SCALE 0.17677669529663687f

// workspace layout (bytes)
#define OFF_W    0L          // weights bf16: qkv(49152) proj(16384) fc1(65536) fc2(65536) = 196608 elems
#define OFF_TBL  393216L     // rpe table t[4][225] f32 (head-major)
#define OFF_QKV  458752L     // qkv bf16 [131072][384]   (later reused as x1 f32 [131072][128])
#define OFF_X1   458752L
#define OFF_H    67567616L   // h bf16 [131072][512] (overwrites attn+proj regions, both dead)
#define OFF_ATTN 101122048L  // attn_out bf16 [131072][128]
#define OFF_PROJ 134676480L  // proj_out f32 [131072][128]
// total ws use: 201,785,344 bytes

__device__ __forceinline__ unsigned short f2bf(float f){
  unsigned int u = __float_as_uint(f);
  u += 0x7FFFu + ((u >> 16) & 1u);          // RNE
  return (unsigned short)(u >> 16);
}
__device__ __forceinline__ float bf2f(unsigned short s){
  return __uint_as_float(((unsigned int)s) << 16);
}

// windowed (shifted) row r  <->  original token index.
__device__ __forceinline__ int win_row_to_orig(int r){
  int win = r >> 6, n = r & 63;
  int b = win >> 6, wh = (win >> 3) & 7, ww = win & 7;
  int hs = wh*8 + (n >> 3), wsv = ww*8 + (n & 7);
  return (b << 12) + (((hs + 4) & 63) << 6) + ((wsv + 4) & 63);
}

// ---------------- prep: weights -> bf16, RPE MLP table ----------------
__global__ __launch_bounds__(256) void prep_kernel(
    const float* __restrict__ qkv_w, const float* __restrict__ proj_w,
    const float* __restrict__ fc1_w, const float* __restrict__ fc2_w,
    const float* __restrict__ rpe_w1, const float* __restrict__ rpe_b1,
    const float* __restrict__ rpe_w2,
    unsigned short* __restrict__ wbf, float* __restrict__ tbl)
{
  if (blockIdx.x == 0) {
    int t = threadIdx.x;
    if (t < 225) {
      int a = t / 15, b = t % 15;
      float v0 = (float)(a - 7) * (8.0f / 7.0f);
      float v1 = (float)(b - 7) * (8.0f / 7.0f);
      float c0 = (v0 > 0.f ? 1.f : (v0 < 0.f ? -1.f : 0.f)) * log2f(fabsf(v0) + 1.f) * (1.0f/3.0f);
      float c1 = (v1 > 0.f ? 1.f : (v1 < 0.f ? -1.f : 0.f)) * log2f(fabsf(v1) + 1.f) * (1.0f/3.0f);
      float a0 = 0.f, a1 = 0.f, a2 = 0.f, a3 = 0.f;
      for (int k = 0; k < 512; k++){
        float h = c0 * rpe_w1[2*k] + c1 * rpe_w1[2*k+1] + rpe_b1[k];
        h = fmaxf(h, 0.f);
        a0 += h * rpe_w2[k];
        a1 += h * rpe_w2[512 + k];
        a2 += h * rpe_w2[1024 + k];
        a3 += h * rpe_w2[1536 + k];
      }
      // head-major layout: tbl[h*225 + t]
      tbl[t] = a0; tbl[225 + t] = a1; tbl[450 + t] = a2; tbl[675 + t] = a3;
    }
  } else {
    int e = (blockIdx.x - 1) * 256 + threadIdx.x;   // 0..196607
    float v;
    if (e < 49152)       v = qkv_w[e];
    else if (e < 65536)  v = proj_w[e - 49152];
    else if (e < 131072) v = fc1_w[e - 65536];
    else                 v = fc2_w[e - 131072];
    wbf[e] = f2bf(v);
  }
}

// ---------------- GEMM: out[M][N] = A[M][K] * W[N][K]^T + bias ----------------
// AMODE: 0 = A f32 direct rows, 1 = A f32 with window-gather rows, 2 = A bf16 direct
// EPI:   0 = +bias -> bf16 store, 1 = +bias -> f32 store with window-scatter rows,
//        2 = +bias, exact GELU -> bf16, 3 = +bias -> f32
template<int N, int K, int AMODE, int EPI>
__global__ __launch_bounds__(256) void gemm_kernel(
    const void* __restrict__ Ap, const unsigned short* __restrict__ Bw,
    const float* __restrict__ bias, void* __restrict__ Out)
{
  constexpr int NT = N / 16;
  constexpr int KC = K / 32;
  __shared__ __align__(16) unsigned short bs[N * 40];  // [N][32] bf16, padded to 40 (2-way = free)
  int lane = threadIdx.x & 63;
  int wave = threadIdx.x >> 6;
  int m0 = blockIdx.x * 64 + wave * 16;
  int l15 = lane & 15;
  int kg  = lane >> 4;
  int arow = m0 + l15;
  int ag = (AMODE == 1) ? win_row_to_orig(arow) : arow;

  f32x4_t acc[NT];
#pragma unroll
  for (int t = 0; t < NT; t++) acc[t] = (f32x4_t){0.f, 0.f, 0.f, 0.f};

  for (int kc = 0; kc < KC; ++kc){
    if (kc) __syncthreads();
    // stage W chunk [N][32] bf16 into LDS
    for (int e = threadIdx.x; e < N * 4; e += 256){
      int n = e >> 2, k8 = e & 3;
      short8_t v = *(const short8_t*)(Bw + n * K + kc * 32 + k8 * 8);
      *(short8_t*)(&bs[n * 40 + k8 * 8]) = v;
    }
    __syncthreads();

    short8_t af;
    if (AMODE == 2) {
      af = *(const short8_t*)((const unsigned short*)Ap + (long)ag * K + kc * 32 + kg * 8);
    } else {
      const float* ap = (const float*)Ap + (long)ag * K + kc * 32 + kg * 8;
      f32x4_t a0 = *(const f32x4_t*)ap;
      f32x4_t a1 = *(const f32x4_t*)(ap + 4);
      union { short8_t v; unsigned short u[8]; } pk;
      pk.u[0] = f2bf(a0[0]); pk.u[1] = f2bf(a0[1]); pk.u[2] = f2bf(a0[2]); pk.u[3] = f2bf(a0[3]);
      pk.u[4] = f2bf(a1[0]); pk.u[5] = f2bf(a1[1]); pk.u[6] = f2bf(a1[2]); pk.u[7] = f2bf(a1[3]);
      af = pk.v;
    }
#pragma unroll
    for (int t = 0; t < NT; t++){
      short8_t bf = *(const short8_t*)(&bs[(t * 16 + l15) * 40 + kg * 8]);
      acc[t] = __builtin_amdgcn_mfma_f32_16x16x32_bf16(af, bf, acc[t], 0, 0, 0);
    }
  }

  int orow[4];
#pragma unroll
  for (int i = 0; i < 4; i++){
    int r = m0 + kg * 4 + i;
    orow[i] = (EPI == 1) ? win_row_to_orig(r) : r;
  }
#pragma unroll
  for (int t = 0; t < NT; t++){
    int col = t * 16 + l15;
    float bv = bias[col];
#pragma unroll
    for (int i = 0; i < 4; i++){
      float v = acc[t][i] + bv;
      if (EPI == 0) {
        ((unsigned short*)Out)[(long)orow[i] * N + col] = f2bf(v);
      } else if (EPI == 1) {
        ((float*)Out)[(long)orow[i] * N + col] = v;
      } else if (EPI == 2) {
        float g = 0.5f * v * (1.f + erff(v * 0.70710678118f));
        ((unsigned short*)Out)[(long)orow[i] * N + col] = f2bf(g);
      } else {
        ((float*)Out)[(long)orow[i] * N + col] = v;
      }
    }
  }
}

// ---------------- per-window attention, MFMA version ----------------
// block = 1 window, 4 waves = 4 heads. QK^T and PV on mfma_f32_16x16x32_bf16.
// S stays in C-layout (row q = kg*4+ii + mt*16, col m = nt*16+l15).
// Bias index is separable per 16x16 tile; shift mask reduces to per-tile region
// bits (only wh==7 / ww==7 windows have nonzero regions). Softmax skips the
// max-subtract (|s| = O(1); masked entries exp(-100) -> 0), mathematically
// identical to the reference.
__global__ __launch_bounds__(256) void attn_kernel(
    const unsigned short* __restrict__ qkv, const float* __restrict__ tbl,
    unsigned short* __restrict__ outp)
{
  __shared__ __align__(16) unsigned short vt[NHEAD][32][72];  // V^T, stride 144B: 2-way reads
  __shared__ __align__(16) unsigned short pl[NHEAD][16][72];  // P chunk (one mt tile)
  __shared__ float tl[900];                                   // bias table [head][225]
  int win  = blockIdx.x;
  int head = threadIdx.x >> 6;
  int lane = threadIdx.x & 63;
  int l15 = lane & 15, kg = lane >> 4;

  for (int e = threadIdx.x; e < 900; e += 256) tl[e] = tbl[e];

  const unsigned short* qbase = qkv + (long)win * 64 * 384;

  // V transpose staging: lane owns tok = lane, writes u16 columns (conflict-free pairs)
  {
    const unsigned short* vp = qbase + lane * 384 + 256 + head * 32;
#pragma unroll
    for (int d0 = 0; d0 < 4; d0++){
      union { short8_t v; unsigned short u[8]; } pk;
      pk.v = *(const short8_t*)(vp + d0 * 8);
#pragma unroll
      for (int j = 0; j < 8; j++)
        vt[head][d0 * 8 + j][lane] = pk.u[j];
    }
  }

  // K fragments (B-operand): row nt*16+l15 of K, 8 contiguous d at kg*8
  short8_t kf[4];
#pragma unroll
  for (int nt = 0; nt < 4; nt++)
    kf[nt] = *(const short8_t*)(qbase + (nt * 16 + l15) * 384 + 128 + head * 32 + kg * 8);

  __syncthreads();   // tl ready (vt/pl are within-wave)

  // B_V fragments: V^T[dt*16+l15][ks*32+kg*8 ..+8]
  short8_t bvf[2][2];
#pragma unroll
  for (int dt = 0; dt < 2; dt++)
#pragma unroll
    for (int ks = 0; ks < 2; ks++)
      bvf[dt][ks] = *(const short8_t*)(&vt[head][dt * 16 + l15][ks * 32 + kg * 8]);

  const float* tlh = tl + head * 225;
  bool wh7 = ((win >> 3) & 7) == 7;
  bool ww7 = (win & 7) == 7;
  bool crq_lt = (kg & 1) == 0;          // (q&7) < 4, independent of ii
  bool crm_lt = (l15 & 7) < 4;          // (m&7) < 4
  int  t3m_lo = l15 >> 3;               // (m>>3) & 1 within nt tile
  int  dj0 = (kg & 1) * 4 - (l15 & 7) + 7;

#pragma unroll
  for (int mt = 0; mt < 4; mt++){
    // A-frag: Q row mt*16+l15, 8 contiguous d at kg*8
    short8_t qf = *(const short8_t*)(qbase + (mt * 16 + l15) * 384 + head * 32 + kg * 8);
    f32x4_t sacc[4];
#pragma unroll
    for (int nt = 0; nt < 4; nt++)
      sacc[nt] = __builtin_amdgcn_mfma_f32_16x16x32_bf16(qf, kf[nt], (f32x4_t){0.f,0.f,0.f,0.f}, 0, 0, 0);

    int t3q = mt * 2 + (kg >> 1);       // q>>3
    bool rrq_lt = t3q < 4;
    float p[4][4];
#pragma unroll
    for (int nt = 0; nt < 4; nt++){
      int t3m = nt * 2 + t3m_lo;        // m>>3
      const float* bp = tlh + (t3q - t3m + 7) * 15 + dj0;
      bool masked = (wh7 && (rrq_lt != (t3m < 4))) || (ww7 && (crq_lt != crm_lt));
      float mterm = masked ? -100.f : 0.f;
#pragma unroll
      for (int ii = 0; ii < 4; ii++){
        float s = sacc[nt][ii] * SCALE + bp[ii] + mterm;
        p[nt][ii] = __expf(s);
      }
    }
    // row sums across the 16-lane l15 group (4 kg groups stay disjoint under xor<16)
    float inv[4];
#pragma unroll
    for (int ii = 0; ii < 4; ii++){
      float sm = (p[0][ii] + p[1][ii]) + (p[2][ii] + p[3][ii]);
      sm += __shfl_xor(sm, 1); sm += __shfl_xor(sm, 2);
      sm += __shfl_xor(sm, 4); sm += __shfl_xor(sm, 8);
      inv[ii] = 1.f / sm;
    }
    // P chunk -> LDS (bf16); same-wave in-order DS + may-alias keeps write<read
#pragma unroll
    for (int nt = 0; nt < 4; nt++)
#pragma unroll
      for (int ii = 0; ii < 4; ii++)
        pl[head][kg * 4 + ii][nt * 16 + l15] = f2bf(p[nt][ii]);

    asm volatile("s_waitcnt lgkmcnt(0)" ::: "memory");

    f32x4_t oacc[2] = {{0.f,0.f,0.f,0.f},{0.f,0.f,0.f,0.f}};
#pragma unroll
    for (int ks = 0; ks < 2; ks++){
      short8_t pa = *(const short8_t*)(&pl[head][l15][ks * 32 + kg * 8]);
#pragma unroll
      for (int dt = 0; dt < 2; dt++)
        oacc[dt] = __builtin_amdgcn_mfma_f32_16x16x32_bf16(pa, bvf[dt][ks], oacc[dt], 0, 0, 0);
    }

    unsigned short* op = outp + ((long)(win * 64 + mt * 16 + kg * 4)) * 128 + head * 32;
#pragma unroll
    for (int ii = 0; ii < 4; ii++)
#pragma unroll
      for (int dt = 0; dt < 2; dt++)
        op[ii * 128 + dt * 16 + l15] = f2bf(oacc[dt][ii] * inv[ii]);
  }
}

// ---------------- out = res + LayerNorm(in) * w + b ----------------
// NOTE: no __restrict__ on in/out — LN2 runs in-place on d_out.
__global__ __launch_bounds__(256) void ln_residual_kernel(
    const float* in, const float* __restrict__ res,
    const float* __restrict__ w, const float* __restrict__ b, float* out)
{
  int row = blockIdx.x * 4 + (threadIdx.x >> 6);
  int lane = threadIdx.x & 63;
  long base = (long)row * 128 + lane * 2;
  f32x2_t v = *(const f32x2_t*)(in + base);
  float sm = v[0] + v[1];
#pragma unroll
  for (int off = 1; off < 64; off <<= 1) sm += __shfl_xor(sm, off);
  float mu = sm * 0.0078125f;
  float d0 = v[0] - mu, d1 = v[1] - mu;
  float qv = d0 * d0 + d1 * d1;
#pragma unroll
  for (int off = 1; off < 64; off <<= 1) qv += __shfl_xor(qv, off);
  float rs = rsqrtf(qv * 0.0078125f + 1e-5f);
  f32x2_t r = *(const f32x2_t*)(res + base);
  f32x2_t o;
  o[0] = r[0] + d0 * rs * w[lane*2]     + b[lane*2];
  o[1] = r[1] + d1 * rs * w[lane*2 + 1] + b[lane*2 + 1];
  *(f32x2_t*)(out + base) = o;
}

extern "C" void kernel_launch(void* const* d_in, const int* in_sizes, int n_in,
                              void* d_out, int out_size, void* d_ws, size_t ws_size,
                              hipStream_t stream)
{
  (void)in_sizes; (void)n_in; (void)out_size; (void)ws_size;
  const float* x      = (const float*)d_in[0];
  const float* qkv_w  = (const float*)d_in[1];
  const float* qkv_b  = (const float*)d_in[2];
  const float* proj_w = (const float*)d_in[3];
  const float* proj_b = (const float*)d_in[4];
  const float* rpe_w1 = (const float*)d_in[5];
  const float* rpe_b1 = (const float*)d_in[6];
  const float* rpe_w2 = (const float*)d_in[7];
  const float* n1w    = (const float*)d_in[8];
  const float* n1b    = (const float*)d_in[9];
  const float* fc1_w  = (const float*)d_in[10];
  const float* fc1_b  = (const float*)d_in[11];
  const float* fc2_w  = (const float*)d_in[12];
  const float* fc2_b  = (const float*)d_in[13];
  const float* n2w    = (const float*)d_in[14];
  const float* n2b    = (const float*)d_in[15];

  char* ws = (char*)d_ws;
  unsigned short* Wbf   = (unsigned short*)(ws + OFF_W);
  float*          tblp  = (float*)(ws + OFF_TBL);
  unsigned short* qkvp  = (unsigned short*)(ws + OFF_QKV);
  unsigned short* attnp = (unsigned short*)(ws + OFF_ATTN);
  float*          projp = (float*)(ws + OFF_PROJ);
  float*          x1p   = (float*)(ws + OFF_X1);
  unsigned short* hp    = (unsigned short*)(ws + OFF_H);
  float*          yp    = (float*)d_out;

  prep_kernel<<<769, 256, 0, stream>>>(qkv_w, proj_w, fc1_w, fc2_w, rpe_w1, rpe_b1, rpe_w2, Wbf, tblp);
  // QKV: windowed rows, gather x through roll+partition
  gemm_kernel<384, 128, 1, 0><<<2048, 256, 0, stream>>>(x, Wbf, qkv_b, qkvp);
  attn_kernel<<<2048, 256, 0, stream>>>(qkvp, tblp, attnp);
  // proj: scatter rows back to original token order
  gemm_kernel<128, 128, 2, 1><<<2048, 256, 0, stream>>>(attnp, Wbf + 49152, proj_b, projp);
  ln_residual_kernel<<<32768, 256, 0, stream>>>(projp, x, n1w, n1b, x1p);
  gemm_kernel<512, 128, 0, 2><<<2048, 256, 0, stream>>>(x1p, Wbf + 65536, fc1_b, hp);
  gemm_kernel<128, 512, 2, 3><<<2048, 256, 0, stream>>>(hp, Wbf + 131072, fc2_b, yp);
  ln_residual_kernel<<<32768, 256, 0, stream>>>(yp, x1p, n2w, n2b, (float*)d_out);
}

// Round 4
// 438.405 us; speedup vs baseline: 1.4773x; 1.1606x over previous
//
#include <hip/hip_runtime.h>
#include <hip/hip_bf16.h>

typedef __attribute__((ext_vector_type(8))) short short8_t;
typedef __attribute__((ext_vector_type(4))) float f32x4_t;
typedef __attribute__((ext_vector_type(2))) float f32x2_t;

#define NHEAD 4
#define SCALE 0.17677669529663687f

// workspace layout (bytes) — total 168,230,912 (proven budget >= 201.8 MB)
#define OFF_W    0L           // weights bf16: qkv(49152) proj(16384) fc1(65536) fc2(65536)
#define OFF_TBL  393216L      // rpe table t[4][225] f32 (head-major)
#define OFF_QKV  458752L      // qkv bf16 [131072][384]; later hp bf16 [131072][512] overlays
#define OFF_H    458752L
#define OFF_ATTN 101122048L   // attn_out bf16 [131072][128] (dead after proj)
#define OFF_X1BF 134676480L   // x1 bf16 [131072][128] (fc1 A + fc2 residual)

__device__ __forceinline__ unsigned short f2bf(float f){
  unsigned int u = __float_as_uint(f);
  u += 0x7FFFu + ((u >> 16) & 1u);          // RNE
  return (unsigned short)(u >> 16);
}
__device__ __forceinline__ float bf2f(unsigned short s){
  return __uint_as_float(((unsigned int)s) << 16);
}

// windowed (shifted) row r -> original token index
__device__ __forceinline__ int win_row_to_orig(int r){
  int win = r >> 6, n = r & 63;
  int b = win >> 6, wh = (win >> 3) & 7, ww = win & 7;
  int hs = wh*8 + (n >> 3), wsv = ww*8 + (n & 7);
  return (b << 12) + (((hs + 4) & 63) << 6) + ((wsv + 4) & 63);
}

// exact-GELU via Abramowitz-Stegun 7.1.26 erf (abs err <= 1.5e-7)
__device__ __forceinline__ float gelu_exact(float x){
  float z  = x * 0.70710678118654752f;
  float az = fabsf(z);
  float t  = __builtin_amdgcn_rcpf(1.0f + 0.3275911f * az);
  float poly = t*(0.254829592f + t*(-0.284496736f + t*(1.421413741f +
               t*(-1.453152027f + t*1.061405429f))));
  float er = 1.0f - poly * __expf(-z*z);
  er = (z < 0.f) ? -er : er;
  return 0.5f * x * (1.0f + er);
}

// ---------------- prep: weights -> bf16, RPE MLP table ----------------
__global__ __launch_bounds__(256) void prep_kernel(
    const float* __restrict__ qkv_w, const float* __restrict__ proj_w,
    const float* __restrict__ fc1_w, const float* __restrict__ fc2_w,
    const float* __restrict__ rpe_w1, const float* __restrict__ rpe_b1,
    const float* __restrict__ rpe_w2,
    unsigned short* __restrict__ wbf, float* __restrict__ tbl)
{
  if (blockIdx.x == 0) {
    int t = threadIdx.x;
    if (t < 225) {
      int a = t / 15, b = t % 15;
      float v0 = (float)(a - 7) * (8.0f / 7.0f);
      float v1 = (float)(b - 7) * (8.0f / 7.0f);
      float c0 = (v0 > 0.f ? 1.f : (v0 < 0.f ? -1.f : 0.f)) * log2f(fabsf(v0) + 1.f) * (1.0f/3.0f);
      float c1 = (v1 > 0.f ? 1.f : (v1 < 0.f ? -1.f : 0.f)) * log2f(fabsf(v1) + 1.f) * (1.0f/3.0f);
      float a0 = 0.f, a1 = 0.f, a2 = 0.f, a3 = 0.f;
      for (int k = 0; k < 512; k++){
        float h = c0 * rpe_w1[2*k] + c1 * rpe_w1[2*k+1] + rpe_b1[k];
        h = fmaxf(h, 0.f);
        a0 += h * rpe_w2[k];
        a1 += h * rpe_w2[512 + k];
        a2 += h * rpe_w2[1024 + k];
        a3 += h * rpe_w2[1536 + k];
      }
      tbl[t] = a0; tbl[225 + t] = a1; tbl[450 + t] = a2; tbl[675 + t] = a3;
    }
  } else {
    int e = (blockIdx.x - 1) * 256 + threadIdx.x;   // 0..196607
    float v;
    if (e < 49152)       v = qkv_w[e];
    else if (e < 65536)  v = proj_w[e - 49152];
    else if (e < 131072) v = fc1_w[e - 65536];
    else                 v = fc2_w[e - 131072];
    wbf[e] = f2bf(v);
  }
}

// ---------------- flavor A GEMM: A-panel in registers, B-frags from L2 ----------------
// out[M][N] = A[M][K=128] * W[N][K]^T + bias. 4 waves/block, 64 rows/wave.
// No LDS, no barriers. AMODE: 1 = A f32 + window-gather, 2 = A bf16 direct.
// EPI: 0 = bias -> bf16, 2 = bias + exact GELU -> bf16.
template<int N, int AMODE, int EPI>
__global__ __launch_bounds__(256) void gemm_a_kernel(
    const void* __restrict__ Ap, const unsigned short* __restrict__ Bw,
    const float* __restrict__ bias, unsigned short* __restrict__ Out)
{
  constexpr int K  = 128;
  constexpr int NC = N / 32;
  int lane = threadIdx.x & 63;
  int wave = threadIdx.x >> 6;
  int l15 = lane & 15, kg = lane >> 4;
  int m0 = (blockIdx.x * 4 + wave) * 64;

  short8_t a[4][4];
#pragma unroll
  for (int mr = 0; mr < 4; mr++){
    int r = m0 + mr*16 + l15;
    if (AMODE == 1) r = win_row_to_orig(r);
    if (AMODE == 2){
      const unsigned short* ap = (const unsigned short*)Ap + (long)r * K + kg * 8;
#pragma unroll
      for (int kc = 0; kc < 4; kc++)
        a[mr][kc] = *(const short8_t*)(ap + kc * 32);
    } else {
      const float* ap = (const float*)Ap + (long)r * K + kg * 8;
#pragma unroll
      for (int kc = 0; kc < 4; kc++){
        f32x4_t a0 = *(const f32x4_t*)(ap + kc * 32);
        f32x4_t a1 = *(const f32x4_t*)(ap + kc * 32 + 4);
        union { short8_t v; unsigned short u[8]; } pk;
        pk.u[0] = f2bf(a0[0]); pk.u[1] = f2bf(a0[1]); pk.u[2] = f2bf(a0[2]); pk.u[3] = f2bf(a0[3]);
        pk.u[4] = f2bf(a1[0]); pk.u[5] = f2bf(a1[1]); pk.u[6] = f2bf(a1[2]); pk.u[7] = f2bf(a1[3]);
        a[mr][kc] = pk.v;
      }
    }
  }

  const unsigned short* bp0 = Bw + (long)l15 * K + kg * 8;

#pragma unroll 2
  for (int nc = 0; nc < NC; nc++){
    short8_t b[2][4];
#pragma unroll
    for (int nr = 0; nr < 2; nr++)
#pragma unroll
      for (int kc = 0; kc < 4; kc++)
        b[nr][kc] = *(const short8_t*)(bp0 + (long)(nc*32 + nr*16) * K + kc * 32);

    f32x4_t acc[4][2];
#pragma unroll
    for (int mr = 0; mr < 4; mr++)
#pragma unroll
      for (int nr = 0; nr < 2; nr++) acc[mr][nr] = (f32x4_t){0.f,0.f,0.f,0.f};
#pragma unroll
    for (int kc = 0; kc < 4; kc++)
#pragma unroll
      for (int mr = 0; mr < 4; mr++)
#pragma unroll
        for (int nr = 0; nr < 2; nr++)
          acc[mr][nr] = __builtin_amdgcn_mfma_f32_16x16x32_bf16(a[mr][kc], b[nr][kc], acc[mr][nr], 0, 0, 0);

#pragma unroll
    for (int nr = 0; nr < 2; nr++){
      int col = nc*32 + nr*16 + l15;
      float bv = bias[col];
#pragma unroll
      for (int mr = 0; mr < 4; mr++)
#pragma unroll
        for (int i = 0; i < 4; i++){
          float v = acc[mr][nr][i] + bv;
          if (EPI == 2) v = gelu_exact(v);
          Out[(long)(m0 + mr*16 + kg*4 + i) * N + col] = f2bf(v);
        }
    }
  }
}

// ---------------- flavor B GEMM + fused LayerNorm-residual ----------------
// out_row = res_row + LN(A[row]*W^T + bias) * lnw + lnb.  N = 128 fixed.
// 4 waves/block, 32 rows/wave, full output row per lane-group -> LN in epilogue.
// SCATTER: windowed row -> orig row on output/residual. RESBF: residual dtype.
// OUTBF: output dtype.
template<int K, int SCATTER, int RESBF, int OUTBF>
__global__ __launch_bounds__(256) void gemm_b_ln_kernel(
    const unsigned short* __restrict__ Ap, const unsigned short* __restrict__ Bw,
    const float* __restrict__ bias,
    const float* __restrict__ lnw, const float* __restrict__ lnb,
    const void* __restrict__ Res, void* __restrict__ OutP)
{
  constexpr int KC = K / 32;
  int lane = threadIdx.x & 63;
  int wave = threadIdx.x >> 6;
  int l15 = lane & 15, kg = lane >> 4;
  int m0 = (blockIdx.x * 4 + wave) * 32;

  f32x4_t acc[2][8];
#pragma unroll
  for (int mr = 0; mr < 2; mr++)
#pragma unroll
    for (int nt = 0; nt < 8; nt++) acc[mr][nt] = (f32x4_t){0.f,0.f,0.f,0.f};

  const unsigned short* ap0 = Ap + (long)(m0 + l15) * K + kg * 8;
  const unsigned short* bp0 = Bw + (long)l15 * K + kg * 8;

#pragma unroll 2
  for (int kc = 0; kc < KC; kc++){
    short8_t a0 = *(const short8_t*)(ap0 + kc * 32);
    short8_t a1 = *(const short8_t*)(ap0 + 16 * K + kc * 32);
    short8_t b[8];
#pragma unroll
    for (int nt = 0; nt < 8; nt++)
      b[nt] = *(const short8_t*)(bp0 + (long)nt * 16 * K + kc * 32);
#pragma unroll
    for (int nt = 0; nt < 8; nt++)
      acc[0][nt] = __builtin_amdgcn_mfma_f32_16x16x32_bf16(a0, b[nt], acc[0][nt], 0, 0, 0);
#pragma unroll
    for (int nt = 0; nt < 8; nt++)
      acc[1][nt] = __builtin_amdgcn_mfma_f32_16x16x32_bf16(a1, b[nt], acc[1][nt], 0, 0, 0);
  }

  float bv[8], wv[8], bb[8];
#pragma unroll
  for (int nt = 0; nt < 8; nt++){
    int col = nt*16 + l15;
    bv[nt] = bias[col]; wv[nt] = lnw[col]; bb[nt] = lnb[col];
  }

#pragma unroll
  for (int mr = 0; mr < 2; mr++)
#pragma unroll
    for (int i = 0; i < 4; i++){
      float v[8];
      float s1 = 0.f, s2 = 0.f;
#pragma unroll
      for (int nt = 0; nt < 8; nt++){
        v[nt] = acc[mr][nt][i] + bv[nt];
        s1 += v[nt]; s2 += v[nt]*v[nt];
      }
      // row reduce across the 16-lane l15 group (kg groups hold distinct rows)
      s1 += __shfl_xor(s1, 1); s2 += __shfl_xor(s2, 1);
      s1 += __shfl_xor(s1, 2); s2 += __shfl_xor(s2, 2);
      s1 += __shfl_xor(s1, 4); s2 += __shfl_xor(s2, 4);
      s1 += __shfl_xor(s1, 8); s2 += __shfl_xor(s2, 8);
      float mu = s1 * 0.0078125f;
      float var = s2 * 0.0078125f - mu * mu;
      float rs = rsqrtf(var + 1e-5f);
      int row = m0 + mr*16 + kg*4 + i;
      int orow = SCATTER ? win_row_to_orig(row) : row;
      long rb = (long)orow * 128;
#pragma unroll
      for (int nt = 0; nt < 8; nt++){
        int col = nt*16 + l15;
        float r = RESBF ? bf2f(((const unsigned short*)Res)[rb + col])
                        : ((const float*)Res)[rb + col];
        float o = r + (v[nt] - mu) * rs * wv[nt] + bb[nt];
        if (OUTBF) ((unsigned short*)OutP)[rb + col] = f2bf(o);
        else       ((float*)OutP)[rb + col] = o;
      }
    }
}

// ---------------- per-window attention, MFMA (unchanged from R3) ----------------
__global__ __launch_bounds__(256) void attn_kernel(
    const unsigned short* __restrict__ qkv, const float* __restrict__ tbl,
    unsigned short* __restrict__ outp)
{
  __shared__ __align__(16) unsigned short vt[NHEAD][32][72];
  __shared__ __align__(16) unsigned short pl[NHEAD][16][72];
  __shared__ float tl[900];
  int win  = blockIdx.x;
  int head = threadIdx.x >> 6;
  int lane = threadIdx.x & 63;
  int l15 = lane & 15, kg = lane >> 4;

  for (int e = threadIdx.x; e < 900; e += 256) tl[e] = tbl[e];

  const unsigned short* qbase = qkv + (long)win * 64 * 384;

  {
    const unsigned short* vp = qbase + lane * 384 + 256 + head * 32;
#pragma unroll
    for (int d0 = 0; d0 < 4; d0++){
      union { short8_t v; unsigned short u[8]; } pk;
      pk.v = *(const short8_t*)(vp + d0 * 8);
#pragma unroll
      for (int j = 0; j < 8; j++)
        vt[head][d0 * 8 + j][lane] = pk.u[j];
    }
  }

  short8_t kf[4];
#pragma unroll
  for (int nt = 0; nt < 4; nt++)
    kf[nt] = *(const short8_t*)(qbase + (nt * 16 + l15) * 384 + 128 + head * 32 + kg * 8);

  __syncthreads();

  short8_t bvf[2][2];
#pragma unroll
  for (int dt = 0; dt < 2; dt++)
#pragma unroll
    for (int ks = 0; ks < 2; ks++)
      bvf[dt][ks] = *(const short8_t*)(&vt[head][dt * 16 + l15][ks * 32 + kg * 8]);

  const float* tlh = tl + head * 225;
  bool wh7 = ((win >> 3) & 7) == 7;
  bool ww7 = (win & 7) == 7;
  bool crq_lt = (kg & 1) == 0;
  bool crm_lt = (l15 & 7) < 4;
  int  t3m_lo = l15 >> 3;
  int  dj0 = (kg & 1) * 4 - (l15 & 7) + 7;

#pragma unroll
  for (int mt = 0; mt < 4; mt++){
    short8_t qf = *(const short8_t*)(qbase + (mt * 16 + l15) * 384 + head * 32 + kg * 8);
    f32x4_t sacc[4];
#pragma unroll
    for (int nt = 0; nt < 4; nt++)
      sacc[nt] = __builtin_amdgcn_mfma_f32_16x16x32_bf16(qf, kf[nt], (f32x4_t){0.f,0.f,0.f,0.f}, 0, 0, 0);

    int t3q = mt * 2 + (kg >> 1);
    bool rrq_lt = t3q < 4;
    float p[4][4];
#pragma unroll
    for (int nt = 0; nt < 4; nt++){
      int t3m = nt * 2 + t3m_lo;
      const float* bp = tlh + (t3q - t3m + 7) * 15 + dj0;
      bool masked = (wh7 && (rrq_lt != (t3m < 4))) || (ww7 && (crq_lt != crm_lt));
      float mterm = masked ? -100.f : 0.f;
#pragma unroll
      for (int ii = 0; ii < 4; ii++){
        float s = sacc[nt][ii] * SCALE + bp[ii] + mterm;
        p[nt][ii] = __expf(s);
      }
    }
    float inv[4];
#pragma unroll
    for (int ii = 0; ii < 4; ii++){
      float sm = (p[0][ii] + p[1][ii]) + (p[2][ii] + p[3][ii]);
      sm += __shfl_xor(sm, 1); sm += __shfl_xor(sm, 2);
      sm += __shfl_xor(sm, 4); sm += __shfl_xor(sm, 8);
      inv[ii] = 1.f / sm;
    }
#pragma unroll
    for (int nt = 0; nt < 4; nt++)
#pragma unroll
      for (int ii = 0; ii < 4; ii++)
        pl[head][kg * 4 + ii][nt * 16 + l15] = f2bf(p[nt][ii]);

    asm volatile("s_waitcnt lgkmcnt(0)" ::: "memory");

    f32x4_t oacc[2] = {{0.f,0.f,0.f,0.f},{0.f,0.f,0.f,0.f}};
#pragma unroll
    for (int ks = 0; ks < 2; ks++){
      short8_t pa = *(const short8_t*)(&pl[head][l15][ks * 32 + kg * 8]);
#pragma unroll
      for (int dt = 0; dt < 2; dt++)
        oacc[dt] = __builtin_amdgcn_mfma_f32_16x16x32_bf16(pa, bvf[dt][ks], oacc[dt], 0, 0, 0);
    }

    unsigned short* op = outp + ((long)(win * 64 + mt * 16 + kg * 4)) * 128 + head * 32;
#pragma unroll
    for (int ii = 0; ii < 4; ii++)
#pragma unroll
      for (int dt = 0; dt < 2; dt++)
        op[ii * 128 + dt * 16 + l15] = f2bf(oacc[dt][ii] * inv[ii]);
  }
}

extern "C" void kernel_launch(void* const* d_in, const int* in_sizes, int n_in,
                              void* d_out, int out_size, void* d_ws, size_t ws_size,
                              hipStream_t stream)
{
  (void)in_sizes; (void)n_in; (void)out_size; (void)ws_size;
  const float* x      = (const float*)d_in[0];
  const float* qkv_w  = (const float*)d_in[1];
  const float* qkv_b  = (const float*)d_in[2];
  const float* proj_w = (const float*)d_in[3];
  const float* proj_b = (const float*)d_in[4];
  const float* rpe_w1 = (const float*)d_in[5];
  const float* rpe_b1 = (const float*)d_in[6];
  const float* rpe_w2 = (const float*)d_in[7];
  const float* n1w    = (const float*)d_in[8];
  const float* n1b    = (const float*)d_in[9];
  const float* fc1_w  = (const float*)d_in[10];
  const float* fc1_b  = (const float*)d_in[11];
  const float* fc2_w  = (const float*)d_in[12];
  const float* fc2_b  = (const float*)d_in[13];
  const float* n2w    = (const float*)d_in[14];
  const float* n2b    = (const float*)d_in[15];

  char* ws = (char*)d_ws;
  unsigned short* Wbf   = (unsigned short*)(ws + OFF_W);
  float*          tblp  = (float*)(ws + OFF_TBL);
  unsigned short* qkvp  = (unsigned short*)(ws + OFF_QKV);
  unsigned short* attnp = (unsigned short*)(ws + OFF_ATTN);
  unsigned short* x1bf  = (unsigned short*)(ws + OFF_X1BF);
  unsigned short* hp    = (unsigned short*)(ws + OFF_H);

  prep_kernel<<<769, 256, 0, stream>>>(qkv_w, proj_w, fc1_w, fc2_w, rpe_w1, rpe_b1, rpe_w2, Wbf, tblp);
  // QKV: gather x through roll+window, A f32 -> bf16 in-reg, out windowed order
  gemm_a_kernel<384, 1, 0><<<512, 256, 0, stream>>>(x, Wbf, qkv_b, qkvp);
  attn_kernel<<<2048, 256, 0, stream>>>(qkvp, tblp, attnp);
  // proj + LN1 + residual(x), scatter to orig rows, out bf16 x1
  gemm_b_ln_kernel<128, 1, 0, 1><<<1024, 256, 0, stream>>>(
      attnp, Wbf + 49152, proj_b, n1w, n1b, x, x1bf);
  // fc1 + exact GELU -> h bf16 (overlays qkv+attn regions, both dead)
  gemm_a_kernel<512, 2, 2><<<512, 256, 0, stream>>>(x1bf, Wbf + 65536, fc1_b, hp);
  // fc2 + LN2 + residual(x1bf) -> d_out f32
  gemm_b_ln_kernel<512, 0, 1, 0><<<1024, 256, 0, stream>>>(
      hp, Wbf + 131072, fc2_b, n2w, n2b, x1bf, d_out);
}